// Round 9
// baseline (188.036 us; speedup 1.0000x reference)
//
#include <hip/hip_runtime.h>
#include <hip/hip_bf16.h>
#include <math.h>

#define N_TOKENS 8192
#define DIM      512
#define N_TOOLS  50
#define PARAM_DIM 256
#define N_ROWBLK (N_TOKENS / 64)   // 128
#define LDSS 72                    // LDS stride per 64-k region (2-way bank aliasing max)
#define BSREG (64 * LDSS)          // 4608 shorts per k-tile region

typedef float  f32x4 __attribute__((ext_vector_type(4)));
typedef short  s16x8 __attribute__((ext_vector_type(8)));
typedef short  s16x4 __attribute__((ext_vector_type(4)));

// ---- workspace layout (ints) ----
#define WS_IDX     0        // 8192  token -> expert
#define WS_HIST    8192     // 128*50 per-rowblock histograms
#define WS_COUNTS  14592    // 64
#define WS_OFFSETS 14656    // 64
#define WS_ORDER   14720    // 8192
#define WS_XH      32768    // x hi bf16: 8192*512 shorts = 2,097,152 ints

__device__ inline float bf2f(short s) {
    return __uint_as_float(((unsigned)(unsigned short)s) << 16);
}

__device__ inline s16x4 pk4(float a, float b, float c, float d) {
    __hip_bfloat162 p0 = __float22bfloat162_rn(make_float2(a, b));
    __hip_bfloat162 p1 = __float22bfloat162_rn(make_float2(c, d));
    union { __hip_bfloat162 h; short2 s; } u0, u1;
    u0.h = p0; u1.h = p1;
    s16x4 r; r[0] = u0.s.x; r[1] = u0.s.y; r[2] = u1.s.x; r[3] = u1.s.y;
    return r;
}

__device__ inline s16x8 cat8(s16x4 a, s16x4 b) {
    s16x8 r;
    r[0] = a[0]; r[1] = a[1]; r[2] = a[2]; r[3] = a[3];
    r[4] = b[0]; r[5] = b[1]; r[6] = b[2]; r[7] = b[3];
    return r;
}

// ---------------- fused head: params (tiles 0-3, stage-once B) + logits (tile 4) ----------------
// grid (5, 128), block 256 (4 waves). BM=64.
// params tiles: whole-K B staged once (73.7 KB LDS) -> ONE barrier, then barrier-free
//   K-loop with A per-lane direct from x fp32 (converted inline).
// logits tile: split-bf16 per-ktile loop (Bs+Bl), A inline hi+lo from x; writes xh.
__global__ __launch_bounds__(256) void head_mfma(const float* __restrict__ x,
                                                 const float* __restrict__ pw,
                                                 const float* __restrict__ pb,
                                                 const float* __restrict__ rw,
                                                 const float* __restrict__ rb,
                                                 float* __restrict__ out_params,
                                                 float* __restrict__ probs,
                                                 float* __restrict__ out_idx,
                                                 int* __restrict__ idx_i,
                                                 int* __restrict__ hist,
                                                 short* __restrict__ xh) {
    int r0 = blockIdx.y * 64;
    bool isl = (blockIdx.x == 4);
    int c0 = blockIdx.x * 64;

    __shared__ short Bs[8 * BSREG];   // 73728 B; logits tile aliases regions 0 (hi) and 1 (lo)
    __shared__ int rowcol[64];

    int tid = threadIdx.x;
    int wv = tid >> 6;
    int lane = tid & 63;
    int fm = lane & 15;
    int q = lane >> 4;

    int row = r0 + wv * 16 + fm;
    const float* ax = x + (size_t)row * DIM + q * 8;   // lane's A row, base at k=q*8

    f32x4 acc[4] = {{0.f, 0.f, 0.f, 0.f}, {0.f, 0.f, 0.f, 0.f},
                    {0.f, 0.f, 0.f, 0.f}, {0.f, 0.f, 0.f, 0.f}};

    if (!isl) {
        // ---- params tile: stage whole-K B once ----
#pragma unroll
        for (int i = 0; i < 32; ++i) {
            int u = i * 256 + tid;
            int col = u >> 7, g = u & 127;            // g = float4 granule along K
            float4 v = *(const float4*)&pw[(size_t)(c0 + col) * DIM + g * 4];
            int kt = g >> 4, kw = (g & 15) * 4;
            *(s16x4*)&Bs[kt * BSREG + col * LDSS + kw] = pk4(v.x, v.y, v.z, v.w);
        }
        __syncthreads();   // the ONLY barrier

        float4 f0 = *(const float4*)(ax);
        float4 f1 = *(const float4*)(ax + 4);
        float4 f2 = *(const float4*)(ax + 32);
        float4 f3 = *(const float4*)(ax + 36);

        for (int kt = 0; kt < 8; ++kt) {
            float4 n0, n1, n2, n3;
            if (kt < 7) {
                const float* axn = ax + (kt + 1) * 64;
                n0 = *(const float4*)(axn);
                n1 = *(const float4*)(axn + 4);
                n2 = *(const float4*)(axn + 32);
                n3 = *(const float4*)(axn + 36);
            }
            s16x8 a0 = cat8(pk4(f0.x, f0.y, f0.z, f0.w), pk4(f1.x, f1.y, f1.z, f1.w));
            s16x8 a1 = cat8(pk4(f2.x, f2.y, f2.z, f2.w), pk4(f3.x, f3.y, f3.z, f3.w));
#pragma unroll
            for (int kk = 0; kk < 64; kk += 32) {
                s16x8 a = kk ? a1 : a0;
#pragma unroll
                for (int n = 0; n < 4; ++n) {
                    s16x8 b = *(const s16x8*)&Bs[kt * BSREG + (n * 16 + fm) * LDSS + kk + q * 8];
                    acc[n] = __builtin_amdgcn_mfma_f32_16x16x32_bf16(a, b, acc[n], 0, 0, 0);
                }
            }
            f0 = n0; f1 = n1; f2 = n2; f3 = n3;
        }

        float bias[4];
#pragma unroll
        for (int n = 0; n < 4; ++n) bias[n] = pb[c0 + n * 16 + fm];
#pragma unroll
        for (int r = 0; r < 4; ++r) {
            int orow = r0 + wv * 16 + q * 4 + r;
            float* op = out_params + (size_t)orow * PARAM_DIM + c0;
#pragma unroll
            for (int n = 0; n < 4; ++n) op[n * 16 + fm] = acc[n][r] + bias[n];
        }
    } else {
        // ---- logits tile: split-bf16 (3 MFMAs), per-ktile B staging, writes xh ----
        short* BsL = Bs;            // hi region
        short* BlL = Bs + BSREG;    // lo region
        int col[4], g[4];
        const float* bptr[4];
#pragma unroll
        for (int i = 0; i < 4; ++i) {
            int u = i * 256 + tid;
            col[i] = u >> 4; g[i] = u & 15;
            bptr[i] = rw + (size_t)col[i] * DIM + g[i] * 4;
        }
        float4 bpre[4];
#pragma unroll
        for (int i = 0; i < 4; ++i) {
            float4 v = {0.f, 0.f, 0.f, 0.f};
            if (col[i] < N_TOOLS) v = *(const float4*)bptr[i];
            bpre[i] = v;
        }
        float4 f0 = *(const float4*)(ax);
        float4 f1 = *(const float4*)(ax + 4);
        float4 f2 = *(const float4*)(ax + 32);
        float4 f3 = *(const float4*)(ax + 36);

        for (int kt = 0; kt < 8; ++kt) {
            // stage B hi+lo for this ktile
#pragma unroll
            for (int i = 0; i < 4; ++i) {
                float4 v = bpre[i];
                s16x4 h = pk4(v.x, v.y, v.z, v.w);
                *(s16x4*)&BsL[col[i] * LDSS + g[i] * 4] = h;
                s16x4 l = pk4(v.x - bf2f(h[0]), v.y - bf2f(h[1]),
                              v.z - bf2f(h[2]), v.w - bf2f(h[3]));
                *(s16x4*)&BlL[col[i] * LDSS + g[i] * 4] = l;
            }
            __syncthreads();

            // A hi+lo from current fp32, write xh
            s16x4 h0 = pk4(f0.x, f0.y, f0.z, f0.w);
            s16x4 h1 = pk4(f1.x, f1.y, f1.z, f1.w);
            s16x4 h2 = pk4(f2.x, f2.y, f2.z, f2.w);
            s16x4 h3 = pk4(f3.x, f3.y, f3.z, f3.w);
            s16x8 a0h = cat8(h0, h1), a1h = cat8(h2, h3);
            s16x8 a0l = cat8(pk4(f0.x - bf2f(h0[0]), f0.y - bf2f(h0[1]), f0.z - bf2f(h0[2]), f0.w - bf2f(h0[3])),
                             pk4(f1.x - bf2f(h1[0]), f1.y - bf2f(h1[1]), f1.z - bf2f(h1[2]), f1.w - bf2f(h1[3])));
            s16x8 a1l = cat8(pk4(f2.x - bf2f(h2[0]), f2.y - bf2f(h2[1]), f2.z - bf2f(h2[2]), f2.w - bf2f(h2[3])),
                             pk4(f3.x - bf2f(h3[0]), f3.y - bf2f(h3[1]), f3.z - bf2f(h3[2]), f3.w - bf2f(h3[3])));
            *(s16x8*)&xh[(size_t)row * DIM + kt * 64 + q * 8] = a0h;
            *(s16x8*)&xh[(size_t)row * DIM + kt * 64 + 32 + q * 8] = a1h;

            // prefetch next ktile
            if (kt < 7) {
                const float* axn = ax + (kt + 1) * 64;
                f0 = *(const float4*)(axn);
                f1 = *(const float4*)(axn + 4);
                f2 = *(const float4*)(axn + 32);
                f3 = *(const float4*)(axn + 36);
#pragma unroll
                for (int i = 0; i < 4; ++i) {
                    float4 v = {0.f, 0.f, 0.f, 0.f};
                    if (col[i] < N_TOOLS) v = *(const float4*)(bptr[i] + (kt + 1) * 64);
                    bpre[i] = v;
                }
            }

#pragma unroll
            for (int kk = 0; kk < 64; kk += 32) {
                s16x8 ah = kk ? a1h : a0h;
                s16x8 al = kk ? a1l : a0l;
#pragma unroll
                for (int n = 0; n < 4; ++n) {
                    int bo = (n * 16 + fm) * LDSS + kk + q * 8;
                    s16x8 b  = *(const s16x8*)&BsL[bo];
                    s16x8 bl = *(const s16x8*)&BlL[bo];
                    acc[n] = __builtin_amdgcn_mfma_f32_16x16x32_bf16(ah, b,  acc[n], 0, 0, 0);
                    acc[n] = __builtin_amdgcn_mfma_f32_16x16x32_bf16(ah, bl, acc[n], 0, 0, 0);
                    acc[n] = __builtin_amdgcn_mfma_f32_16x16x32_bf16(al, b,  acc[n], 0, 0, 0);
                }
            }
            __syncthreads();
        }

        float rbv[4];
#pragma unroll
        for (int n = 0; n < 4; ++n) {
            int c = n * 16 + fm;
            rbv[n] = (c < N_TOOLS) ? rb[c] : 0.f;
        }
#pragma unroll
        for (int rr = 0; rr < 4; ++rr) {
            int row_l = wv * 16 + q * 4 + rr;
            int orow = r0 + row_l;
            float v[4];
            float vmax = -INFINITY; int vcol = N_TOOLS;
#pragma unroll
            for (int n = 0; n < 4; ++n) {
                int c = n * 16 + fm;
                v[n] = acc[n][rr] + rbv[n];
                if (c < N_TOOLS && v[n] > vmax) { vmax = v[n]; vcol = c; }
            }
#pragma unroll
            for (int s = 1; s < 16; s <<= 1) {
                float om = __shfl_xor(vmax, s, 64);
                int   oc = __shfl_xor(vcol, s, 64);
                if (om > vmax || (om == vmax && oc < vcol)) { vmax = om; vcol = oc; }
            }
            float e[4]; float esum = 0.f;
#pragma unroll
            for (int n = 0; n < 4; ++n) {
                int c = n * 16 + fm;
                e[n] = (c < N_TOOLS) ? expf(v[n] - vmax) : 0.f;
                esum += e[n];
            }
#pragma unroll
            for (int s = 1; s < 16; s <<= 1) esum += __shfl_xor(esum, s, 64);
            float inv = 1.f / esum;
#pragma unroll
            for (int n = 0; n < 4; ++n) {
                int c = n * 16 + fm;
                if (c < N_TOOLS) probs[(size_t)orow * N_TOOLS + c] = e[n] * inv;
            }
            if (fm == 0) {
                out_idx[orow] = (float)vcol;
                idx_i[orow] = vcol;
                rowcol[row_l] = vcol;
            }
        }
        __syncthreads();
        if (wv == 0) {
            int myc = rowcol[lane];
            int cnt = 0;
            for (int e2 = 0; e2 < N_TOOLS; ++e2) {
                unsigned long long m = __ballot(myc == e2);
                if (lane == e2) cnt = __popcll(m);
            }
            if (lane < N_TOOLS) hist[blockIdx.y * N_TOOLS + lane] = cnt;
        }
    }
}

// ---------------- fused scan + reorder: one block, 1024 threads (16 waves) ----------------
__global__ __launch_bounds__(1024) void scan_reorder(const int* __restrict__ hist,
                                                     const int* __restrict__ idx_i,
                                                     int* __restrict__ counts,
                                                     int* __restrict__ offsets,
                                                     int* __restrict__ order) {
    __shared__ int phist[N_ROWBLK * N_TOOLS];   // 25.6 KB
    __shared__ int cnt_s[64];
    __shared__ int off_s[64];
    int l = threadIdx.x & 63;
    int w = threadIdx.x >> 6;   // 16 waves

    for (int e = w; e < N_TOOLS; e += 16) {
        int v0 = hist[l * N_TOOLS + e];
        int v1 = hist[(64 + l) * N_TOOLS + e];
        int s0 = v0;
#pragma unroll
        for (int s = 1; s < 64; s <<= 1) {
            int t = __shfl_up(s0, s, 64);
            if (l >= s) s0 += t;
        }
        int tot0 = __shfl(s0, 63, 64);
        int s1 = v1;
#pragma unroll
        for (int s = 1; s < 64; s <<= 1) {
            int t = __shfl_up(s1, s, 64);
            if (l >= s) s1 += t;
        }
        s1 += tot0;
        phist[l * N_TOOLS + e] = s0 - v0;
        phist[(64 + l) * N_TOOLS + e] = s1 - v1;
        if (l == 63) cnt_s[e] = s1;
    }
    __syncthreads();

    if (w == 0) {
        int c = (l < N_TOOLS) ? cnt_s[l] : 0;
        int pre = c;
#pragma unroll
        for (int s = 1; s < 64; s <<= 1) {
            int v = __shfl_up(pre, s, 64);
            if (l >= s) pre += v;
        }
        off_s[l] = pre - c;
        if (l < N_TOOLS) { offsets[l] = pre - c; counts[l] = c; }
    }
    __syncthreads();

    unsigned long long lt = (1ull << l) - 1ull;
    for (int bb = w; bb < N_ROWBLK; bb += 16) {
        int t = bb * 64 + l;
        int e = idx_i[t];
        int rank = 0;
        for (int ex = 0; ex < N_TOOLS; ++ex) {
            unsigned long long m = __ballot(e == ex);
            if (e == ex) rank = __popcll(m & lt);
        }
        order[off_s[e] + phist[bb * N_TOOLS + e] + rank] = t;
    }
}

// ---------------- adapted: per-expert stage-once GEMM ----------------
// grid (8 col-tiles, 50 experts), block 256 (4 waves). Whole-K B (64 cols, 73.7 KB)
// staged ONCE from expert_w fp32, then barrier-free chunk loop (64 tokens/chunk):
// A gathered per-lane direct from xh, acc in regs, MFMA only.
__global__ __launch_bounds__(256) void adapted_mfma(const short* __restrict__ xh,
                                                    const float* __restrict__ ew,
                                                    const float* __restrict__ eb,
                                                    const int* __restrict__ order,
                                                    const int* __restrict__ offsets,
                                                    const int* __restrict__ counts,
                                                    float* __restrict__ out) {
    int e = blockIdx.y;
    int cnt = counts[e];
    if (cnt == 0) return;
    int c0 = blockIdx.x * 64;
    int start = offsets[e];

    __shared__ short Bs[8 * BSREG];   // 73728 B

    int tid = threadIdx.x;
    int wv = tid >> 6;
    int lane = tid & 63;
    int fm = lane & 15;
    int q = lane >> 4;

    const float* We = ew + (size_t)e * DIM * DIM;
#pragma unroll
    for (int i = 0; i < 32; ++i) {
        int u = i * 256 + tid;
        int col = u >> 7, g = u & 127;
        float4 v = *(const float4*)&We[(size_t)(c0 + col) * DIM + g * 4];
        int kt = g >> 4, kw = (g & 15) * 4;
        *(s16x4*)&Bs[kt * BSREG + col * LDSS + kw] = pk4(v.x, v.y, v.z, v.w);
    }
    __syncthreads();   // the ONLY barrier

    float bias[4];
#pragma unroll
    for (int n = 0; n < 4; ++n) bias[n] = eb[(size_t)e * DIM + c0 + n * 16 + fm];

    for (int m0 = 0; m0 < cnt; m0 += 64) {
        int idxA = m0 + wv * 16 + fm;
        int tokA = (idxA < cnt) ? order[start + idxA] : 0;   // row 0 dummy, discarded
        const short* aph = xh + (size_t)tokA * DIM + q * 8;

        f32x4 acc[4] = {{0.f, 0.f, 0.f, 0.f}, {0.f, 0.f, 0.f, 0.f},
                        {0.f, 0.f, 0.f, 0.f}, {0.f, 0.f, 0.f, 0.f}};

        s16x8 a0 = *(const s16x8*)(aph);
        s16x8 a1 = *(const s16x8*)(aph + 32);
        for (int kt = 0; kt < 8; ++kt) {
            s16x8 a0n, a1n;
            if (kt < 7) {
                a0n = *(const s16x8*)(aph + (kt + 1) * 64);
                a1n = *(const s16x8*)(aph + (kt + 1) * 64 + 32);
            }
#pragma unroll
            for (int kk = 0; kk < 64; kk += 32) {
                s16x8 a = kk ? a1 : a0;
#pragma unroll
                for (int n = 0; n < 4; ++n) {
                    s16x8 b = *(const s16x8*)&Bs[kt * BSREG + (n * 16 + fm) * LDSS + kk + q * 8];
                    acc[n] = __builtin_amdgcn_mfma_f32_16x16x32_bf16(a, b, acc[n], 0, 0, 0);
                }
            }
            a0 = a0n; a1 = a1n;
        }

#pragma unroll
        for (int r = 0; r < 4; ++r) {
            int idxE = m0 + wv * 16 + q * 4 + r;
            if (idxE >= cnt) continue;
            int tokE = order[start + idxE];
            float* op = out + (size_t)tokE * DIM + c0;
#pragma unroll
            for (int n = 0; n < 4; ++n) op[n * 16 + fm] = acc[n][r] + bias[n];
        }
    }
}

extern "C" void kernel_launch(void* const* d_in, const int* in_sizes, int n_in,
                              void* d_out, int out_size, void* d_ws, size_t ws_size,
                              hipStream_t stream) {
    const float* x        = (const float*)d_in[0];
    const float* router_w = (const float*)d_in[1];
    const float* router_b = (const float*)d_in[2];
    const float* expert_w = (const float*)d_in[3];
    const float* expert_b = (const float*)d_in[4];
    const float* param_w  = (const float*)d_in[5];
    const float* param_b  = (const float*)d_in[6];

    float* out = (float*)d_out;
    float* out_idx     = out;                                  // 8192
    float* out_probs   = out + N_TOKENS;                       // 409600
    float* out_adapted = out + N_TOKENS + N_TOKENS * N_TOOLS;  // 4194304
    float* out_params  = out_adapted + (size_t)N_TOKENS * DIM; // 2097152

    int* ws = (int*)d_ws;
    int* ws_idx     = ws + WS_IDX;
    int* ws_hist    = ws + WS_HIST;
    int* ws_counts  = ws + WS_COUNTS;
    int* ws_offsets = ws + WS_OFFSETS;
    int* ws_order   = ws + WS_ORDER;
    short* ws_xh    = (short*)(ws + WS_XH);

    head_mfma<<<dim3(5, N_ROWBLK), 256, 0, stream>>>(x, param_w, param_b,
                                                     router_w, router_b,
                                                     out_params, out_probs,
                                                     out_idx, ws_idx, ws_hist, ws_xh);

    scan_reorder<<<1, 1024, 0, stream>>>(ws_hist, ws_idx, ws_counts, ws_offsets, ws_order);

    adapted_mfma<<<dim3(8, N_TOOLS), 256, 0, stream>>>(ws_xh, expert_w, expert_b,
                                                       ws_order, ws_offsets, ws_counts,
                                                       out_adapted);
}